// Round 2
// baseline (359.420 us; speedup 1.0000x reference)
//
#include <hip/hip_runtime.h>
#include <math.h>

#define BSZ   4096
#define NVIEW 2
#define NROWS 8192
#define DIM   128
#define DPAD  132          // +4 floats pad: 16B-aligned rows, 2-way LDS bank alias (free)
#define EPSC  1e-12f

#define BM 64
#define BN 64
#define JSPLIT 4
#define JRANGE (NROWS / JSPLIT)   // 2048
#define NJT (JRANGE / BN)         // 32

// Pass 1: view-major restack + L2 row-normalize; also zero s[] and out[0].
__global__ __launch_bounds__(256) void norm_zero_kernel(
    const float* __restrict__ feat, float* __restrict__ cf,
    float* __restrict__ s, float* __restrict__ out)
{
    int t = blockIdx.x * 256 + threadIdx.x;
    if (t < NROWS) s[t] = 0.0f;
    if (t == 0) out[0] = 0.0f;

    int row  = t >> 6;          // one wave per row, 8192 waves
    int lane = t & 63;
    int v = row >> 12;          // row / 4096
    int b = row & 4095;
    const float* src = feat + (size_t)b * (NVIEW * DIM) + (size_t)v * DIM;
    float2 x = *(const float2*)(src + lane * 2);
    float ss = x.x * x.x + x.y * x.y;
    #pragma unroll
    for (int m = 32; m >= 1; m >>= 1) ss += __shfl_xor(ss, m, 64);
    float inv = 1.0f / sqrtf(ss);
    float2 o; o.x = x.x * inv; o.y = x.y * inv;
    *(float2*)(cf + (size_t)row * DIM + lane * 2) = o;
}

// Pass 2: implicit Gram tiles; fuse dist->adc->exp and accumulate row sums
// (self term excluded). s[i] += partial via atomicAdd (JSPLIT partials/row).
__global__ __launch_bounds__(256) void gram_kernel(
    const float* __restrict__ cf, float* __restrict__ s)
{
    __shared__ float lds_a[BM * DPAD];
    __shared__ float lds_b[BN * DPAD];
    int t  = threadIdx.x;
    int tx = t & 15;
    int ty = t >> 4;
    int rb = blockIdx.x >> 2;        // / JSPLIT
    int js = blockIdx.x & (JSPLIT - 1);
    int i0 = rb * BM;
    int j0base = js * JRANGE;

    // stage A tile (64 rows x 128 f32), reused across all j-tiles
    #pragma unroll
    for (int it = 0; it < 8; ++it) {
        int idx = t + it * 256;      // float4 index within tile
        int r   = idx >> 5;
        int k4  = idx & 31;
        float4 v = *(const float4*)(cf + (size_t)(i0 + r) * DIM + k4 * 4);
        *(float4*)(lds_a + r * DPAD + k4 * 4) = v;
    }

    float sexp[4] = {0.f, 0.f, 0.f, 0.f};

    for (int jt = 0; jt < NJT; ++jt) {
        int j0 = j0base + jt * BN;
        __syncthreads();             // protect lds_b readers of previous tile
        #pragma unroll
        for (int it = 0; it < 8; ++it) {
            int idx = t + it * 256;
            int r   = idx >> 5;
            int k4  = idx & 31;
            float4 v = *(const float4*)(cf + (size_t)(j0 + r) * DIM + k4 * 4);
            *(float4*)(lds_b + r * DPAD + k4 * 4) = v;
        }
        __syncthreads();

        float acc[4][4];
        #pragma unroll
        for (int r = 0; r < 4; ++r)
            #pragma unroll
            for (int c = 0; c < 4; ++c) acc[r][c] = 0.f;

        #pragma unroll 4
        for (int k4 = 0; k4 < 32; ++k4) {
            float4 a[4], b[4];
            #pragma unroll
            for (int r = 0; r < 4; ++r)   // broadcast across 16-lane groups
                a[r] = *(const float4*)(lds_a + (ty + 16 * r) * DPAD + k4 * 4);
            #pragma unroll
            for (int c = 0; c < 4; ++c)   // stride-132: 2-way bank alias only
                b[c] = *(const float4*)(lds_b + (tx + 16 * c) * DPAD + k4 * 4);
            #pragma unroll
            for (int r = 0; r < 4; ++r)
                #pragma unroll
                for (int c = 0; c < 4; ++c) {
                    acc[r][c] = fmaf(a[r].x, b[c].x, acc[r][c]);
                    acc[r][c] = fmaf(a[r].y, b[c].y, acc[r][c]);
                    acc[r][c] = fmaf(a[r].z, b[c].z, acc[r][c]);
                    acc[r][c] = fmaf(a[r].w, b[c].w, acc[r][c]);
                }
        }

        // epilogue: dist -> adc -> exp, skip diagonal
        #pragma unroll
        for (int r = 0; r < 4; ++r) {
            int i = i0 + ty + 16 * r;
            #pragma unroll
            for (int c = 0; c < 4; ++c) {
                int j = j0 + tx + 16 * c;
                float g   = acc[r][c];
                float t2  = fmaxf(2.0f - 2.0f * g, EPSC);
                float adc = 1.0f - sqrtf(t2);
                float e   = __expf(adc);
                sexp[r] += (i == j) ? 0.0f : e;
            }
        }
    }

    // reduce across the 16 tx lanes sharing each row, then one atomic per row
    #pragma unroll
    for (int r = 0; r < 4; ++r) {
        float v = sexp[r];
        #pragma unroll
        for (int m = 1; m <= 8; m <<= 1) v += __shfl_xor(v, m, 64);
        if (tx == 0) atomicAdd(&s[i0 + ty + 16 * r], v);
    }
}

// Pass 3: partner dot + loss = mean(log(s_i) - adc_partner)
__global__ __launch_bounds__(1024) void finish_kernel(
    const float* __restrict__ cf, const float* __restrict__ s,
    float* __restrict__ out)
{
    __shared__ float red[16];
    int w    = threadIdx.x >> 6;
    int lane = threadIdx.x & 63;
    int i = blockIdx.x * 16 + w;
    int p = (i + BSZ) & (NROWS - 1);
    float2 x = *(const float2*)(cf + (size_t)i * DIM + lane * 2);
    float2 y = *(const float2*)(cf + (size_t)p * DIM + lane * 2);
    float d = x.x * y.x + x.y * y.y;
    #pragma unroll
    for (int m = 32; m >= 1; m >>= 1) d += __shfl_xor(d, m, 64);
    if (lane == 0) {
        float t2  = fmaxf(2.0f - 2.0f * d, EPSC);
        float adc = 1.0f - sqrtf(t2);
        red[w] = logf(s[i]) - adc;
    }
    __syncthreads();
    if (threadIdx.x == 0) {
        float acc = 0.f;
        #pragma unroll
        for (int k = 0; k < 16; ++k) acc += red[k];
        atomicAdd(out, acc * (1.0f / NROWS));
    }
}

extern "C" void kernel_launch(void* const* d_in, const int* in_sizes, int n_in,
                              void* d_out, int out_size, void* d_ws, size_t ws_size,
                              hipStream_t stream)
{
    const float* feat = (const float*)d_in[0];
    float* out = (float*)d_out;
    float* cf  = (float*)d_ws;                       // 8192*128 f32 = 4 MB
    float* s   = cf + (size_t)NROWS * DIM;           // 8192 f32

    norm_zero_kernel<<<(NROWS * 64) / 256, 256, 0, stream>>>(feat, cf, s, out);
    gram_kernel<<<(NROWS / BM) * JSPLIT, 256, 0, stream>>>(cf, s);
    finish_kernel<<<NROWS / 16, 1024, 0, stream>>>(cf, s, out);
}

// Round 3
// 173.480 us; speedup vs baseline: 2.0718x; 2.0718x over previous
//
#include <hip/hip_runtime.h>
#include <math.h>

#define BSZ   4096
#define NVIEW 2
#define NROWS 8192
#define DIM   128
#define EPSC  1e-12f

#define JS  8                 // column splits -> 64 * 8 = 512 blocks
#define NJT 8                 // j-tiles of 128 per block: (8192/JS)/128

using short8 = __attribute__((ext_vector_type(8))) short;
using f32x4  = __attribute__((ext_vector_type(4))) float;

typedef __attribute__((address_space(1))) const unsigned int gas_u32;
typedef __attribute__((address_space(3))) unsigned int       las_u32;

__device__ __forceinline__ void stage16(const void* g, void* l) {
    __builtin_amdgcn_global_load_lds((gas_u32*)g, (las_u32*)l, 16, 0, 0);
}

__device__ __forceinline__ unsigned short f2bf(float x) {
    unsigned int u = __float_as_uint(x);
    unsigned int r = (u + 0x7FFF + ((u >> 16) & 1)) >> 16;   // RNE
    return (unsigned short)r;
}
__device__ __forceinline__ float bf2f(unsigned short b) {
    return __uint_as_float(((unsigned int)b) << 16);
}

// Pass 1: view-major restack + L2 row-normalize. Writes fp32 cf (for finish),
// and bf16 hi/lo split arrays in PRE-SWIZZLED row layout (elem e -> e ^ ((row&7)<<3))
// so gram's global_load_lds(linear) + swizzled ds_read_b128 is conflict-free.
// Also zeros s[] and out[0].
__global__ __launch_bounds__(256) void norm_zero_kernel(
    const float* __restrict__ feat, float* __restrict__ cf,
    unsigned short* __restrict__ hi, unsigned short* __restrict__ lo,
    float* __restrict__ s, float* __restrict__ out)
{
    int t = blockIdx.x * 256 + threadIdx.x;
    if (t < NROWS) s[t] = 0.0f;
    if (t == 0) out[0] = 0.0f;

    int row  = t >> 6;          // one wave per row
    int lane = t & 63;
    int v = row >> 12;
    int b = row & 4095;
    const float* src = feat + (size_t)b * (NVIEW * DIM) + (size_t)v * DIM;
    float2 x = *(const float2*)(src + lane * 2);
    float ss = x.x * x.x + x.y * x.y;
    #pragma unroll
    for (int m = 32; m >= 1; m >>= 1) ss += __shfl_xor(ss, m, 64);
    float inv = 1.0f / sqrtf(ss);
    float2 o; o.x = x.x * inv; o.y = x.y * inv;
    *(float2*)(cf + (size_t)row * DIM + lane * 2) = o;

    unsigned short h0 = f2bf(o.x), h1 = f2bf(o.y);
    unsigned short l0 = f2bf(o.x - bf2f(h0)), l1 = f2bf(o.y - bf2f(h1));
    int e  = lane * 2;
    int es = e ^ ((row & 7) << 3);      // pair stays adjacent (mask flips bits>=3)
    ushort2 hv; hv.x = h0; hv.y = h1;
    ushort2 lv; lv.x = l0; lv.y = l1;
    *(ushort2*)(hi + (size_t)row * DIM + es) = hv;
    *(ushort2*)(lo + (size_t)row * DIM + es) = lv;
}

// Pass 2: bf16-split MFMA gram, fused dist->adc->exp row-sum accumulation.
// Block: 256 thr = 4 waves (2x2), tile 128x128, K=128 fully resident.
// A staged once, B restaged per j-tile. 128 KB LDS -> 1 block/CU.
__global__ __launch_bounds__(256) void gram_kernel(
    const unsigned short* __restrict__ hi, const unsigned short* __restrict__ lo,
    float* __restrict__ s)
{
    __shared__ unsigned short a_hi[128 * 128];
    __shared__ unsigned short a_lo[128 * 128];
    __shared__ unsigned short b_hi[128 * 128];
    __shared__ unsigned short b_lo[128 * 128];

    int t    = threadIdx.x;
    int w    = t >> 6;
    int lane = t & 63;
    int r16  = lane & 15;
    int g    = lane >> 4;
    int wr   = w >> 1, wc = w & 1;
    int rb   = blockIdx.x >> 3;        // / JS
    int js   = blockIdx.x & (JS - 1);
    int i0   = rb * 128;
    int rowbase = wr * 64;

    // stage A tile (rows i0..i0+127): 2 x 32KB linear copies
    {
        const unsigned short* gh = hi + (size_t)i0 * DIM;
        const unsigned short* gl = lo + (size_t)i0 * DIM;
        #pragma unroll
        for (int it = 0; it < 8; ++it) {
            int c   = w * 8 + it;                 // 16B chunk id, 32 per buffer
            int off = (c * 64 + lane) * 8;        // ushort elems
            stage16(gh + off, &a_hi[c * 512]);
            stage16(gl + off, &a_lo[c * 512]);
        }
    }

    float rs[4][4];
    #pragma unroll
    for (int a = 0; a < 4; ++a)
        #pragma unroll
        for (int q = 0; q < 4; ++q) rs[a][q] = 0.0f;

    int sw = (lane & 7) << 4;                     // read-side byte swizzle
    int eq[4];
    #pragma unroll
    for (int q = 0; q < 4; ++q) eq[q] = (g * 4 + q) == r16;

    for (int jt = 0; jt < NJT; ++jt) {
        int j0 = js * (NROWS / JS) + jt * 128;
        __syncthreads();                          // prev compute done before overwrite
        {
            const unsigned short* gh = hi + (size_t)j0 * DIM;
            const unsigned short* gl = lo + (size_t)j0 * DIM;
            #pragma unroll
            for (int it = 0; it < 8; ++it) {
                int c   = w * 8 + it;
                int off = (c * 64 + lane) * 8;
                stage16(gh + off, &b_hi[c * 512]);
                stage16(gl + off, &b_lo[c * 512]);
            }
        }
        __syncthreads();                          // drains vmcnt(0): A (first iter) + B ready

        f32x4 acc[4][4];
        #pragma unroll
        for (int fr = 0; fr < 4; ++fr)
            #pragma unroll
            for (int fc = 0; fc < 4; ++fc) acc[fr][fc] = (f32x4){0.f, 0.f, 0.f, 0.f};

        #pragma unroll
        for (int ks = 0; ks < 4; ++ks) {
            int kb = (ks * 64 + g * 16) ^ sw;     // byte offset within 256B row
            short8 ah[4], al[4], bh[4], bl[4];
            #pragma unroll
            for (int f = 0; f < 4; ++f) {
                int ra = (rowbase + f * 16 + r16) * 256 + kb;
                ah[f] = *(const short8*)((const char*)a_hi + ra);
                al[f] = *(const short8*)((const char*)a_lo + ra);
                int rbb = (wc * 64 + f * 16 + r16) * 256 + kb;
                bh[f] = *(const short8*)((const char*)b_hi + rbb);
                bl[f] = *(const short8*)((const char*)b_lo + rbb);
            }
            #pragma unroll
            for (int fr = 0; fr < 4; ++fr)
                #pragma unroll
                for (int fc = 0; fc < 4; ++fc) {
                    acc[fr][fc] = __builtin_amdgcn_mfma_f32_16x16x32_bf16(ah[fr], bh[fc], acc[fr][fc], 0, 0, 0);
                    acc[fr][fc] = __builtin_amdgcn_mfma_f32_16x16x32_bf16(ah[fr], bl[fc], acc[fr][fc], 0, 0, 0);
                    acc[fr][fc] = __builtin_amdgcn_mfma_f32_16x16x32_bf16(al[fr], bh[fc], acc[fr][fc], 0, 0, 0);
                }
        }

        // epilogue: dist -> adc -> exp, accumulate per-row partial sums in regs
        int diag_w = (j0 + wc * 64) == (i0 + rowbase);
        #pragma unroll
        for (int fr = 0; fr < 4; ++fr)
            #pragma unroll
            for (int fc = 0; fc < 4; ++fc)
                #pragma unroll
                for (int q = 0; q < 4; ++q) {
                    float gv = acc[fr][fc][q];
                    float t2 = fmaxf(fmaf(-2.0f, gv, 2.0f), EPSC);
                    float e  = __expf(1.0f - sqrtf(t2));
                    if (diag_w && (fr == fc) && eq[q]) e = 0.0f;
                    rs[fr][q] += e;
                }
    }

    // reduce across the 16 col-lanes of each group, one atomic per row
    #pragma unroll
    for (int fr = 0; fr < 4; ++fr)
        #pragma unroll
        for (int q = 0; q < 4; ++q) {
            float v = rs[fr][q];
            v += __shfl_xor(v, 1, 64);
            v += __shfl_xor(v, 2, 64);
            v += __shfl_xor(v, 4, 64);
            v += __shfl_xor(v, 8, 64);
            if (r16 == 0)
                atomicAdd(&s[i0 + rowbase + fr * 16 + g * 4 + q], v);
        }
}

// Pass 3: partner dot (fp32) + loss = mean(log(s_i) - adc_partner)
__global__ __launch_bounds__(1024) void finish_kernel(
    const float* __restrict__ cf, const float* __restrict__ s,
    float* __restrict__ out)
{
    __shared__ float red[16];
    int w    = threadIdx.x >> 6;
    int lane = threadIdx.x & 63;
    int i = blockIdx.x * 16 + w;
    int p = (i + BSZ) & (NROWS - 1);
    float2 x = *(const float2*)(cf + (size_t)i * DIM + lane * 2);
    float2 y = *(const float2*)(cf + (size_t)p * DIM + lane * 2);
    float d = x.x * y.x + x.y * y.y;
    #pragma unroll
    for (int m = 32; m >= 1; m >>= 1) d += __shfl_xor(d, m, 64);
    if (lane == 0) {
        float t2  = fmaxf(2.0f - 2.0f * d, EPSC);
        float adc = 1.0f - sqrtf(t2);
        red[w] = logf(s[i]) - adc;
    }
    __syncthreads();
    if (threadIdx.x == 0) {
        float acc = 0.f;
        #pragma unroll
        for (int k = 0; k < 16; ++k) acc += red[k];
        atomicAdd(out, acc * (1.0f / NROWS));
    }
}

extern "C" void kernel_launch(void* const* d_in, const int* in_sizes, int n_in,
                              void* d_out, int out_size, void* d_ws, size_t ws_size,
                              hipStream_t stream)
{
    const float* feat = (const float*)d_in[0];
    float* out = (float*)d_out;
    float* cf  = (float*)d_ws;                               // 4 MB fp32
    float* s   = cf + (size_t)NROWS * DIM;                   // 32 KB
    unsigned short* hi = (unsigned short*)(s + NROWS);       // 2 MB bf16 (swizzled)
    unsigned short* lo = hi + (size_t)NROWS * DIM;           // 2 MB bf16 (swizzled)

    norm_zero_kernel<<<(NROWS * 64) / 256, 256, 0, stream>>>(feat, cf, hi, lo, s, out);
    gram_kernel<<<(NROWS / 128) * JS, 256, 0, stream>>>(hi, lo, s);
    finish_kernel<<<NROWS / 16, 1024, 0, stream>>>(cf, s, out);
}

// Round 4
// 95.881 us; speedup vs baseline: 3.7486x; 1.8093x over previous
//
#include <hip/hip_runtime.h>
#include <math.h>

#define BSZ   4096
#define NROWS 8192
#define DIM   128
#define EPSC  1e-12f

#define JS  8                 // column splits: 64 row-blocks * 8 = 512 blocks = 2/CU
#define NJT 8                 // j-tiles of 128 cols per block

typedef _Float16 half8 __attribute__((ext_vector_type(8)));
typedef float    f32x4 __attribute__((ext_vector_type(4)));

typedef __attribute__((address_space(1))) const unsigned int gas_u32;
typedef __attribute__((address_space(3))) unsigned int       las_u32;

// Stage one 32KB B tile (128 rows x 256B) linearly into LDS: 8 chunks/thread.
__device__ __forceinline__ void stageB(_Float16* lds, const char* gsrc, int w, int lane) {
    #pragma unroll
    for (int it = 0; it < 8; ++it) {
        int c = w * 8 + it;                       // 1KB chunk id, 32 per tile
        __builtin_amdgcn_global_load_lds(
            (gas_u32*)(gsrc + c * 1024 + lane * 16),
            (las_u32*)((char*)lds + c * 1024), 16, 0, 0);
    }
}

// Pass 1: view-major restack + L2 row-normalize. Writes fp32 cf (finish pass)
// and ONE fp16 array in XOR-swizzled row layout (byte b -> b ^ ((row&7)<<4)):
// A-frags load it from global with XOR'd addresses; B stages it linearly into
// LDS and ds_reads with the same XOR (rule #21: same involution both sides).
__global__ __launch_bounds__(256) void norm_zero_kernel(
    const float* __restrict__ feat, float* __restrict__ cf,
    unsigned int* __restrict__ hsw, float* __restrict__ s, float* __restrict__ out)
{
    int t = blockIdx.x * 256 + threadIdx.x;
    if (t < NROWS) s[t] = 0.0f;
    if (t == 0) out[0] = 0.0f;

    int row  = t >> 6;          // one wave per row
    int lane = t & 63;
    int v = row >> 12;
    int b = row & 4095;
    const float* src = feat + (size_t)b * 256 + (size_t)v * 128;
    float2 x = *(const float2*)(src + lane * 2);
    float ss = x.x * x.x + x.y * x.y;
    #pragma unroll
    for (int m = 32; m >= 1; m >>= 1) ss += __shfl_xor(ss, m, 64);
    float inv = 1.0f / sqrtf(ss);
    float2 o; o.x = x.x * inv; o.y = x.y * inv;
    *(float2*)(cf + (size_t)row * DIM + lane * 2) = o;

    union { _Float16 h[2]; unsigned int u; } cv;
    cv.h[0] = (_Float16)o.x;
    cv.h[1] = (_Float16)o.y;
    size_t off = (size_t)row * 256 + ((lane * 4) ^ ((row & 7) << 4));
    *(unsigned int*)((char*)hsw + off) = cv.u;
}

// Pass 2: fp16 MFMA gram, A-in-registers, double-buffered B, counted vmcnt.
// 256 thr = 4 waves (2x2 grid), tile 128x128, K=128. LDS 64KB -> 2 blocks/CU.
__global__ __launch_bounds__(256, 2) void gram_kernel(
    const _Float16* __restrict__ h, float* __restrict__ s)
{
    __shared__ _Float16 bbuf[2][128 * 128];       // 2 x 32KB

    int t    = threadIdx.x;
    int w    = t >> 6;
    int lane = t & 63;
    int r16  = lane & 15;
    int g    = lane >> 4;
    int wr   = w >> 1, wc = w & 1;
    int rb   = blockIdx.x >> 3;                   // bid%8 = js -> same-js blocks
    int js   = blockIdx.x & (JS - 1);             // share an XCD L2 (bid%8 = xcd)
    int i0   = rb * 128;
    int rowbase = wr * 64;
    int swz  = (r16 & 7) << 4;
    const char* hb = (const char*)h;

    // A fragments straight into registers (reused across all 8 j-tiles)
    half8 A[4][4];
    #pragma unroll
    for (int f = 0; f < 4; ++f) {
        size_t rowoff = (size_t)(i0 + rowbase + f * 16 + r16) * 256;
        #pragma unroll
        for (int ks = 0; ks < 4; ++ks)
            A[f][ks] = *(const half8*)(hb + rowoff + ((ks * 64 + g * 16) ^ swz));
    }

    stageB(&bbuf[0][0], hb + (size_t)(js * 1024) * 256, w, lane);

    float rs[4][4];
    #pragma unroll
    for (int a = 0; a < 4; ++a)
        #pragma unroll
        for (int q = 0; q < 4; ++q) rs[a][q] = 0.0f;
    int eq[4];
    #pragma unroll
    for (int q = 0; q < 4; ++q) eq[q] = (g * 4 + q) == r16;

    for (int jt = 0; jt < NJT; ++jt) {
        int j0 = js * 1024 + jt * 128;
        if (jt + 1 < NJT) {
            stageB(&bbuf[(jt + 1) & 1][0], hb + (size_t)(j0 + 128) * 256, w, lane);
            asm volatile("s_waitcnt vmcnt(8)" ::: "memory");   // cur tile landed,
        } else {                                               // next stays in flight
            asm volatile("s_waitcnt vmcnt(0)" ::: "memory");
        }
        __builtin_amdgcn_s_barrier();             // all waves see cur staged

        const char* bb = (const char*)&bbuf[jt & 1][0];
        f32x4 acc[4][4];
        #pragma unroll
        for (int fr = 0; fr < 4; ++fr)
            #pragma unroll
            for (int fc = 0; fc < 4; ++fc) acc[fr][fc] = (f32x4){0.f, 0.f, 0.f, 0.f};

        #pragma unroll
        for (int ks = 0; ks < 4; ++ks) {
            half8 B[4];
            #pragma unroll
            for (int fc = 0; fc < 4; ++fc)
                B[fc] = *(const half8*)(bb + (wc * 64 + fc * 16 + r16) * 256
                                           + ((ks * 64 + g * 16) ^ swz));
            #pragma unroll
            for (int fr = 0; fr < 4; ++fr)
                #pragma unroll
                for (int fc = 0; fc < 4; ++fc)
                    acc[fr][fc] = __builtin_amdgcn_mfma_f32_16x16x32_f16(
                        A[fr][ks], B[fc], acc[fr][fc], 0, 0, 0);
        }

        // epilogue: sum exp(-sqrt(t2)); the e^1 factor is folded into finish
        int diag_w = (j0 + wc * 64) == (i0 + rowbase);
        #pragma unroll
        for (int fr = 0; fr < 4; ++fr)
            #pragma unroll
            for (int fc = 0; fc < 4; ++fc)
                #pragma unroll
                for (int q = 0; q < 4; ++q) {
                    float gv = acc[fr][fc][q];
                    float t2 = fmaxf(fmaf(-2.0f, gv, 2.0f), EPSC);
                    float e  = __expf(-__builtin_amdgcn_sqrtf(t2));
                    if (diag_w && (fr == fc) && eq[q]) e = 0.0f;
                    rs[fr][q] += e;
                }
        __builtin_amdgcn_s_barrier();             // cur fully read before overwrite
    }

    // reduce across the 16 col-lanes, one atomic per row
    #pragma unroll
    for (int fr = 0; fr < 4; ++fr)
        #pragma unroll
        for (int q = 0; q < 4; ++q) {
            float v = rs[fr][q];
            v += __shfl_xor(v, 1, 64);
            v += __shfl_xor(v, 2, 64);
            v += __shfl_xor(v, 4, 64);
            v += __shfl_xor(v, 8, 64);
            if (r16 == 0)
                atomicAdd(&s[i0 + rowbase + fr * 16 + g * 4 + q], v);
        }
}

// Pass 3: partner dot (fp32) + loss = mean(1 + log(s'_i) - adc_partner)
// (the +1 restores the e^1 factored out of the gram epilogue)
__global__ __launch_bounds__(1024) void finish_kernel(
    const float* __restrict__ cf, const float* __restrict__ s,
    float* __restrict__ out)
{
    __shared__ float red[16];
    int w    = threadIdx.x >> 6;
    int lane = threadIdx.x & 63;
    int i = blockIdx.x * 16 + w;
    int p = (i + BSZ) & (NROWS - 1);
    float2 x = *(const float2*)(cf + (size_t)i * DIM + lane * 2);
    float2 y = *(const float2*)(cf + (size_t)p * DIM + lane * 2);
    float d = x.x * y.x + x.y * y.y;
    #pragma unroll
    for (int m = 32; m >= 1; m >>= 1) d += __shfl_xor(d, m, 64);
    if (lane == 0) {
        float t2  = fmaxf(2.0f - 2.0f * d, EPSC);
        float adc = 1.0f - sqrtf(t2);
        red[w] = 1.0f + logf(s[i]) - adc;
    }
    __syncthreads();
    if (threadIdx.x == 0) {
        float acc = 0.f;
        #pragma unroll
        for (int k = 0; k < 16; ++k) acc += red[k];
        atomicAdd(out, acc * (1.0f / NROWS));
    }
}

extern "C" void kernel_launch(void* const* d_in, const int* in_sizes, int n_in,
                              void* d_out, int out_size, void* d_ws, size_t ws_size,
                              hipStream_t stream)
{
    const float* feat = (const float*)d_in[0];
    float* out = (float*)d_out;
    float* cf  = (float*)d_ws;                               // 4 MB fp32
    float* s   = cf + (size_t)NROWS * DIM;                   // 32 KB
    unsigned int* hsw = (unsigned int*)(s + NROWS);          // 2 MB fp16 (swizzled)

    norm_zero_kernel<<<(NROWS * 64) / 256, 256, 0, stream>>>(feat, cf, hsw, s, out);
    gram_kernel<<<(NROWS / 128) * JS, 256, 0, stream>>>((const _Float16*)hsw, s);
    finish_kernel<<<NROWS / 16, 1024, 0, stream>>>(cf, s, out);
}